// Round 2
// baseline (438.608 us; speedup 1.0000x reference)
//
#include <hip/hip_runtime.h>
#include <hip/hip_bf16.h>

#define NN   10000
#define NP   10048          // 157*64, padded row count
#define HID  256
#define BN_EPS 1e-5f

typedef __bf16 bf16x4 __attribute__((ext_vector_type(4)));
typedef __bf16 bf16x8 __attribute__((ext_vector_type(8)));
typedef float  f32x4  __attribute__((ext_vector_type(4)));

// async global->LDS, 16B per lane; dest = wave-uniform base + lane*16
__device__ __forceinline__ void gl_lds16(const void* gptr, void* lptr) {
    __builtin_amdgcn_global_load_lds(
        (const __attribute__((address_space(1))) void*)gptr,
        (__attribute__((address_space(3))) void*)lptr,
        16, 0, 0);
}

// ------------------------------------------------------------------
// graph prep
__global__ void detect_i64(const int* __restrict__ e, unsigned* __restrict__ flag) {
    __shared__ int any_nonzero;
    if (threadIdx.x == 0) any_nonzero = 0;
    __syncthreads();
    int v = e[2 * threadIdx.x + 1];
    if (v != 0) any_nonzero = 1;
    __syncthreads();
    if (threadIdx.x == 0) *flag = (any_nonzero == 0) ? 1u : 0u;  // 1 => int64 layout
}

__device__ __forceinline__ int edge_val(const int* e, unsigned f, long idx) {
    return f ? e[2 * idx] : e[idx];
}

__global__ void zero_u32(unsigned* p, int n) {
    int i = blockIdx.x * blockDim.x + threadIdx.x;
    if (i < n) p[i] = 0u;
}

__global__ void count_edges(const int* __restrict__ e, const unsigned* __restrict__ flag,
                            unsigned* __restrict__ cnt, int E) {
    int i = blockIdx.x * blockDim.x + threadIdx.x;
    if (i >= E) return;
    unsigned f = *flag;
    int dst = edge_val(e, f, (long)E + i);
    atomicAdd(&cnt[dst], 1u);
}

__global__ void compute_dinv(const unsigned* __restrict__ cnt, float* __restrict__ dinv, int n) {
    int i = blockIdx.x * blockDim.x + threadIdx.x;
    if (i < n) dinv[i] = rsqrtf((float)cnt[i] + 1.0f);
}

__global__ void scan_offsets(const unsigned* __restrict__ cnt, unsigned* __restrict__ off,
                             unsigned* __restrict__ cur, int n) {
    __shared__ unsigned partial[256];
    int t = threadIdx.x;
    int chunk = (n + 255) / 256;
    int lo = t * chunk;
    int hi = lo + chunk; if (hi > n) hi = n; if (lo > n) lo = n;
    unsigned s = 0;
    for (int i = lo; i < hi; ++i) s += cnt[i];
    partial[t] = s;
    __syncthreads();
    for (int d = 1; d < 256; d <<= 1) {
        unsigned v = (t >= d) ? partial[t - d] : 0u;
        __syncthreads();
        partial[t] += v;
        __syncthreads();
    }
    unsigned base = (t == 0) ? 0u : partial[t - 1];
    for (int i = lo; i < hi; ++i) {
        off[i] = base; cur[i] = base;
        base += cnt[i];
    }
    if (t == 255) off[n] = base;
}

__global__ void fill_csr(const int* __restrict__ e, const unsigned* __restrict__ flag,
                         unsigned* __restrict__ cur, int* __restrict__ csr_src, int E) {
    int i = blockIdx.x * blockDim.x + threadIdx.x;
    if (i >= E) return;
    unsigned f = *flag;
    int src = edge_val(e, f, (long)i);
    int dst = edge_val(e, f, (long)E + i);
    unsigned pos = atomicAdd(&cur[dst], 1u);
    csr_src[pos] = src;
}

// ------------------------------------------------------------------
// split fp32 matrix -> bf16 hi/lo, zero-padding rows to rpad
__global__ void split_mat(const float* __restrict__ src, __bf16* __restrict__ hi,
                          __bf16* __restrict__ lo, int rows, int cols, int rpad) {
    int idx = blockIdx.x * 256 + threadIdx.x;
    int tot = rpad * cols;
    if (idx >= tot) return;
    int r = idx / cols, c = idx - r * cols;
    float v = (r < rows) ? src[(size_t)r * cols + c] : 0.0f;
    __bf16 h = (__bf16)v;
    hi[idx] = h;
    lo[idx] = (__bf16)(v - (float)h);
}

// ------------------------------------------------------------------
// Input projection: C(NP x 256) += x(NN x 2048) * in_W^T, split-K over blockIdx.z
// A: fp32 with fused hi/lo split; B: pre-split bf16 via global_load_lds.
#define IP_KC 512
__global__ __launch_bounds__(256) void inproj_gemm(
    const float* __restrict__ A,
    const __bf16* __restrict__ Bh, const __bf16* __restrict__ Bl,
    float* __restrict__ C)
{
    __shared__ __align__(16) __bf16 sAh[64 * 32], sAl[64 * 32];
    __shared__ __align__(16) __bf16 sBh[256 * 32], sBl[256 * 32];

    const int tid = threadIdx.x, wid = tid >> 6, lane = tid & 63;
    const int fr = lane & 15, fq = lane >> 4;
    const int bm = blockIdx.x * 64;
    const int kbase = blockIdx.z * IP_KC;
    const int wn = wid * 64;

    f32x4 acc[4][4] = {};

    const int rs = tid >> 2;            // 0..63  (A staging row)
    const int cq = tid & 3;             // chunk 0..3
    const int scA = ((cq ^ (rs & 3)) << 3);
    const int brow_l = lane >> 2;       // 0..15 within slice
    const int bch = lane & 3;

    for (int kk = 0; kk < IP_KC; kk += 32) {
        const int k0 = kbase + kk;
        // ---- stage A (fp32 -> split bf16, swizzled ds_write) ----
        {
            int gr = bm + rs; if (gr >= NN) gr = NN - 1;
            const float* ap = A + (size_t)gr * 2048 + k0 + cq * 8;
            float4 v0 = *(const float4*)ap;
            float4 v1 = *(const float4*)(ap + 4);
            float vv[8] = {v0.x, v0.y, v0.z, v0.w, v1.x, v1.y, v1.z, v1.w};
            bf16x8 hv, lv;
#pragma unroll
            for (int j = 0; j < 8; ++j) {
                __bf16 h = (__bf16)vv[j];
                hv[j] = h;
                lv[j] = (__bf16)(vv[j] - (float)h);
            }
            *(bf16x8*)&sAh[rs * 32 + scA] = hv;
            *(bf16x8*)&sAl[rs * 32 + scA] = lv;
        }
        // ---- stage B via global_load_lds (pre-swizzled source) ----
#pragma unroll
        for (int j = 0; j < 4; ++j) {
            int slice = wid * 4 + j;
            int row = slice * 16 + brow_l;          // 0..255
            int lc = bch ^ (row & 3);
            size_t goff = (size_t)row * 2048 + k0 + lc * 8;
            gl_lds16(Bh + goff, &sBh[slice * 512]);
            gl_lds16(Bl + goff, &sBl[slice * 512]);
        }
        __syncthreads();

        bf16x8 bh[4], bl[4];
#pragma unroll
        for (int ni = 0; ni < 4; ++ni) {
            int r = wn + ni * 16 + fr;
            int e = r * 32 + ((fq ^ (r & 3)) << 3);
            bh[ni] = *(const bf16x8*)&sBh[e];
            bl[ni] = *(const bf16x8*)&sBl[e];
        }
#pragma unroll
        for (int mi = 0; mi < 4; ++mi) {
            int r = mi * 16 + fr;
            int e = r * 32 + ((fq ^ (r & 3)) << 3);
            bf16x8 ah = *(const bf16x8*)&sAh[e];
            bf16x8 al = *(const bf16x8*)&sAl[e];
#pragma unroll
            for (int ni = 0; ni < 4; ++ni) {
                acc[mi][ni] = __builtin_amdgcn_mfma_f32_16x16x32_bf16(ah, bh[ni], acc[mi][ni], 0, 0, 0);
                acc[mi][ni] = __builtin_amdgcn_mfma_f32_16x16x32_bf16(ah, bl[ni], acc[mi][ni], 0, 0, 0);
                acc[mi][ni] = __builtin_amdgcn_mfma_f32_16x16x32_bf16(al, bh[ni], acc[mi][ni], 0, 0, 0);
            }
        }
        __syncthreads();
    }

#pragma unroll
    for (int mi = 0; mi < 4; ++mi) {
        int row0 = bm + mi * 16 + fq * 4;
#pragma unroll
        for (int ni = 0; ni < 4; ++ni) {
            int col = wn + ni * 16 + fr;
#pragma unroll
            for (int r = 0; r < 4; ++r)
                atomicAdd(&C[(size_t)(row0 + r) * HID + col], acc[mi][ni][r]);
        }
    }
}

// bias+relu epilogue; emits h as bf16 hi/lo, zero pad rows
__global__ void inproj_epi(const float* __restrict__ acc, const float* __restrict__ b,
                           __bf16* __restrict__ hhi, __bf16* __restrict__ hlo) {
    int idx = blockIdx.x * 256 + threadIdx.x;   // over NP*HID
    int row = idx >> 8, col = idx & 255;
    float v = 0.0f;
    if (row < NN) v = fmaxf(acc[idx] + b[col], 0.0f);
    __bf16 h = (__bf16)v;
    hhi[idx] = h;
    hlo[idx] = (__bf16)(v - (float)h);
}

// ------------------------------------------------------------------
// Pure-bf16 split GEMM: C(M x N) = A * B^T, A: NP x K (hi/lo), B: Npad x K (hi/lo)
// out: fp32 (guarded, stride Nout) or bf16 hi/lo (stride N, all NP rows)
__global__ __launch_bounds__(256) void gemm_bf(
    const __bf16* __restrict__ Ah, const __bf16* __restrict__ Al,
    const __bf16* __restrict__ Bh, const __bf16* __restrict__ Bl,
    const float* __restrict__ bias,
    float* __restrict__ Cf, __bf16* __restrict__ Chi, __bf16* __restrict__ Clo,
    int K, int N, int Nout, int relu)
{
    __shared__ __align__(16) __bf16 sAh[64 * 32], sAl[64 * 32];
    __shared__ __align__(16) __bf16 sBh[64 * 32], sBl[64 * 32];

    const int tid = threadIdx.x, wid = tid >> 6, lane = tid & 63;
    const int fr = lane & 15, fq = lane >> 4;
    const int wr = wid >> 1, wc = wid & 1;
    const int bm = blockIdx.x * 64, bn = blockIdx.y * 64;

    f32x4 acc[2][2] = {};

    const int rl = wid * 16 + (lane >> 2);   // staging row 0..63
    const int lc = (lane & 3) ^ (rl & 3);    // pre-swizzled chunk

    for (int k0 = 0; k0 < K; k0 += 32) {
        size_t aoff = (size_t)(bm + rl) * K + k0 + lc * 8;
        size_t boff = (size_t)(bn + rl) * K + k0 + lc * 8;
        gl_lds16(Ah + aoff, &sAh[wid * 512]);
        gl_lds16(Al + aoff, &sAl[wid * 512]);
        gl_lds16(Bh + boff, &sBh[wid * 512]);
        gl_lds16(Bl + boff, &sBl[wid * 512]);
        __syncthreads();

        bf16x8 bh[2], bl[2];
#pragma unroll
        for (int ni = 0; ni < 2; ++ni) {
            int r = wc * 32 + ni * 16 + fr;
            int e = r * 32 + ((fq ^ (r & 3)) << 3);
            bh[ni] = *(const bf16x8*)&sBh[e];
            bl[ni] = *(const bf16x8*)&sBl[e];
        }
#pragma unroll
        for (int mi = 0; mi < 2; ++mi) {
            int r = wr * 32 + mi * 16 + fr;
            int e = r * 32 + ((fq ^ (r & 3)) << 3);
            bf16x8 ah = *(const bf16x8*)&sAh[e];
            bf16x8 al = *(const bf16x8*)&sAl[e];
#pragma unroll
            for (int ni = 0; ni < 2; ++ni) {
                acc[mi][ni] = __builtin_amdgcn_mfma_f32_16x16x32_bf16(ah, bh[ni], acc[mi][ni], 0, 0, 0);
                acc[mi][ni] = __builtin_amdgcn_mfma_f32_16x16x32_bf16(ah, bl[ni], acc[mi][ni], 0, 0, 0);
                acc[mi][ni] = __builtin_amdgcn_mfma_f32_16x16x32_bf16(al, bh[ni], acc[mi][ni], 0, 0, 0);
            }
        }
        __syncthreads();
    }

#pragma unroll
    for (int mi = 0; mi < 2; ++mi) {
#pragma unroll
        for (int ni = 0; ni < 2; ++ni) {
            int col = bn + wc * 32 + ni * 16 + fr;
            float bb = (bias && col < Nout) ? bias[col] : 0.0f;
#pragma unroll
            for (int r = 0; r < 4; ++r) {
                int row = bm + wr * 32 + mi * 16 + fq * 4 + r;
                float v = acc[mi][ni][r] + bb;
                if (relu) v = fmaxf(v, 0.0f);
                if (Cf) {
                    if (row < NN && col < Nout) Cf[(size_t)row * Nout + col] = v;
                } else {
                    __bf16 h = (__bf16)v;
                    Chi[(size_t)row * N + col] = h;
                    Clo[(size_t)row * N + col] = (__bf16)(v - (float)h);
                }
            }
        }
    }
}

// ------------------------------------------------------------------
// Fused GCN aggregate: out = relu(BN(agg + self + bias)) (+ residual)
// Emits fp32 (optional, for residual) + bf16 hi/lo (for next GEMM); zero pad rows.
__global__ __launch_bounds__(256) void gcn_aggregate(
    const float* __restrict__ hw, const float* __restrict__ res,
    const float* __restrict__ dinv, const unsigned* __restrict__ off,
    const int* __restrict__ csr_src,
    const float* __restrict__ bias, const float* __restrict__ gamma,
    const float* __restrict__ beta, const float* __restrict__ mean,
    const float* __restrict__ var,
    float* __restrict__ hf, __bf16* __restrict__ hhi, __bf16* __restrict__ hlo)
{
    int n = blockIdx.x;
    int f = threadIdx.x;
    size_t idx = (size_t)n * HID + f;
    if (n >= NN) {
        hhi[idx] = (__bf16)0.0f;
        hlo[idx] = (__bf16)0.0f;
        return;
    }
    float dn = dinv[n];
    unsigned j0 = off[n], j1 = off[n + 1];
    float acc = 0.0f;
    for (unsigned j = j0; j < j1; ++j) {
        int s = csr_src[j];
        acc += hw[(size_t)s * HID + f] * dinv[s];
    }
    acc *= dn;
    acc += hw[idx] * dn * dn;
    acc += bias[f];
    acc = (acc - mean[f]) * rsqrtf(var[f] + BN_EPS) * gamma[f] + beta[f];
    acc = fmaxf(acc, 0.0f);
    if (res) acc += res[idx];
    if (hf) hf[idx] = acc;
    __bf16 h = (__bf16)acc;
    hhi[idx] = h;
    hlo[idx] = (__bf16)(acc - (float)h);
}

// ------------------------------------------------------------------
extern "C" void kernel_launch(void* const* d_in, const int* in_sizes, int n_in,
                              void* d_out, int out_size, void* d_ws, size_t ws_size,
                              hipStream_t stream)
{
    const float* x     = (const float*)d_in[0];
    const int*   eidx  = (const int*)d_in[1];
    const float* in_W  = (const float*)d_in[2];
    const float* in_b  = (const float*)d_in[3];
    const float* gcn_W = (const float*)d_in[4];
    const float* gcn_b = (const float*)d_in[5];
    const float* bn_g  = (const float*)d_in[6];
    const float* bn_be = (const float*)d_in[7];
    const float* bn_m  = (const float*)d_in[8];
    const float* bn_v  = (const float*)d_in[9];
    const float* c1_W  = (const float*)d_in[10];
    const float* c1_b  = (const float*)d_in[11];
    const float* c2_W  = (const float*)d_in[12];
    const float* c2_b  = (const float*)d_in[13];
    const float* c3_W  = (const float*)d_in[14];
    const float* c3_b  = (const float*)d_in[15];
    float* out = (float*)d_out;

    const int E = in_sizes[1] / 2;
    float* ws = (float*)d_ws;

    // ---- workspace layout (f32 units) ----
    float*  h1   = ws;                               // NP*HID
    float*  h2   = h1 + (size_t)NP * HID;            // also inproj accumulator
    float*  hw   = h2 + (size_t)NP * HID;
    __bf16* hhi  = (__bf16*)(hw + (size_t)NP * HID); // NP*HID bf16
    __bf16* hlo  = hhi + (size_t)NP * HID;
    __bf16* wih  = hlo + (size_t)NP * HID;           // 256x2048
    __bf16* wil  = wih + 256 * 2048;
    __bf16* gwh  = wil + 256 * 2048;                 // 768x256
    __bf16* gwl  = gwh + 768 * 256;
    __bf16* c1wh = gwl + 768 * 256;                  // 128x256
    __bf16* c1wl = c1wh + 128 * 256;
    __bf16* c2wh = c1wl + 128 * 256;                 // 64x128
    __bf16* c2wl = c2wh + 64 * 128;
    __bf16* c3wh = c2wl + 64 * 128;                  // 64x64 (10 real rows)
    __bf16* c3wl = c3wh + 64 * 64;
    float*    dinv = (float*)(c3wl + 64 * 64);
    unsigned* cnt  = (unsigned*)(dinv + NN);
    unsigned* off  = cnt + NN;
    unsigned* cur  = off + NN + 1;
    unsigned* flag = cur + NN;
    int*      csr  = (int*)(flag + 4);
    // classifier intermediates alias hw (free after last aggregate)
    __bf16* c1oh = (__bf16*)hw;                      // NP*128
    __bf16* c1ol = c1oh + (size_t)NP * 128;
    __bf16* c2oh = c1ol + (size_t)NP * 128;          // NP*64
    __bf16* c2ol = c2oh + (size_t)NP * 64;

    // ---- graph prep ----
    zero_u32<<<(NN + 255) / 256, 256, 0, stream>>>(cnt, NN);
    detect_i64<<<1, 256, 0, stream>>>(eidx, flag);
    count_edges<<<(E + 255) / 256, 256, 0, stream>>>(eidx, flag, cnt, E);
    compute_dinv<<<(NN + 255) / 256, 256, 0, stream>>>(cnt, dinv, NN);
    scan_offsets<<<1, 256, 0, stream>>>(cnt, off, cur, NN);
    fill_csr<<<(E + 255) / 256, 256, 0, stream>>>(eidx, flag, cur, csr, E);

    // ---- weight splits ----
    split_mat<<<2048, 256, 0, stream>>>(in_W, wih, wil, 256, 2048, 256);
    split_mat<<<768, 256, 0, stream>>>(gcn_W, gwh, gwl, 768, 256, 768);
    split_mat<<<128, 256, 0, stream>>>(c1_W, c1wh, c1wl, 128, 256, 128);
    split_mat<<<32, 256, 0, stream>>>(c2_W, c2wh, c2wl, 64, 128, 64);
    split_mat<<<16, 256, 0, stream>>>(c3_W, c3wh, c3wl, 10, 64, 64);

    // ---- input projection (split-K=4, atomic accumulate into h2) ----
    hipMemsetAsync(h2, 0, (size_t)NP * HID * 4, stream);
    inproj_gemm<<<dim3(NP / 64, 1, 2048 / IP_KC), 256, 0, stream>>>(x, wih, wil, h2);
    inproj_epi<<<NP, 256, 0, stream>>>(h2, in_b, hhi, hlo);

    // ---- 3 GCN layers ----
    for (int i = 0; i < 3; ++i) {
        gemm_bf<<<dim3(NP / 64, 4), 256, 0, stream>>>(
            hhi, hlo, gwh + (size_t)i * 256 * 256, gwl + (size_t)i * 256 * 256,
            nullptr, hw, nullptr, nullptr, 256, 256, 256, 0);
        const float* res = (i == 0) ? nullptr : (i == 1 ? h1 : h2);
        float* hf = (i == 0) ? h1 : (i == 1 ? h2 : nullptr);
        gcn_aggregate<<<NP, 256, 0, stream>>>(
            hw, res, dinv, off, csr,
            gcn_b + i * HID, bn_g + i * HID, bn_be + i * HID,
            bn_m + i * HID, bn_v + i * HID, hf, hhi, hlo);
    }

    // ---- classifier ----
    gemm_bf<<<dim3(NP / 64, 2), 256, 0, stream>>>(hhi, hlo, c1wh, c1wl, c1_b,
                                                  nullptr, c1oh, c1ol, 256, 128, 128, 1);
    gemm_bf<<<dim3(NP / 64, 1), 256, 0, stream>>>(c1oh, c1ol, c2wh, c2wl, c2_b,
                                                  nullptr, c2oh, c2ol, 128, 64, 64, 1);
    gemm_bf<<<dim3(NP / 64, 1), 256, 0, stream>>>(c2oh, c2ol, c3wh, c3wl, c3_b,
                                                  out, nullptr, nullptr, 64, 64, 10, 0);
}